// Round 3
// baseline (564.570 us; speedup 1.0000x reference)
//
#include <hip/hip_runtime.h>
#include <hip/hip_bf16.h>
#include <cstdint>
#include <cstddef>

// ---------------------------------------------------------------------------
// STGNN forward. Round 8: gather MLP + full-width GEMM blocks.
//  - R7 post-mortem: fused gather = 104us, 3.4TB/s, VALU 47% -> latency-bound
//    (only 4 rows in flight, deg~8 = 2 serial epochs/phase). Now unrolled to
//    8 partners in flight, with per-phase cnt/aD hoisted to kernel start.
//  - GEMM: old grid (M/64, 4) fetched the A panel 4x (once per 64-col
//    block) ~ 75MB avoidable per big GEMM. Blocks now compute 64x256 output
//    (16 acc/wave, B-tile reused 4x, A fetched once). LDS 25.6KB/block.
//  - Everything else as R7 (single fused gather, int buckets, in-kernel edge
//    weights, zero atomics in hot path).
// ---------------------------------------------------------------------------

#define LRELU_SLOPE 0.2f
#define CAP 64
#define NRANGE 8

typedef __attribute__((ext_vector_type(8))) short short8;
typedef __attribute__((ext_vector_type(4))) float floatx4;

__device__ __forceinline__ float bf2f(ushort u) {
    union { unsigned int u32; float f; } v; v.u32 = ((unsigned int)u) << 16; return v.f;
}
__device__ __forceinline__ ushort f2bf(float x) {
    union { float f; unsigned int u; } v; v.f = x;
    unsigned int r = (v.u + 0x7FFFu + ((v.u >> 16) & 1u)) >> 16;
    return (ushort)r;
}

// ---------------- elementwise fp32 -> bf16 cast (4/thread) ------------------
__global__ __launch_bounds__(256) void cast_bf16(
    const float* __restrict__ x, ushort* __restrict__ y, int n4)
{
    const int idx = blockIdx.x * blockDim.x + threadIdx.x;
    if (idx >= n4) return;
    float4 v = ((const float4*)x)[idx];
    ushort4 o;
    o.x = f2bf(v.x); o.y = f2bf(v.y); o.z = f2bf(v.z); o.w = f2bf(v.w);
    ((ushort4*)y)[idx] = o;
}

// ------------- weight transpose+cast: W[K][256] f32 -> WT[256][K] bf16 ------
__global__ __launch_bounds__(256) void wtrans(
    const float* __restrict__ W, ushort* __restrict__ WT, int K)
{
    const int idx = blockIdx.x * blockDim.x + threadIdx.x;
    if (idx >= K * 256) return;
    const int k = idx >> 8, n = idx & 255;
    WT[n * K + k] = f2bf(W[idx]);
}

// ------- bf16 MFMA GEMM: C[M,256] = act(A[M,K] @ B + bias), 64x256/block ----
// Full 256-col output per block: A tile fetched ONCE, B tile reused 4x.
// Optional fused per-row attention dots for all 4 heads.
__global__ __launch_bounds__(256) void gemm_bf16(
    const ushort* __restrict__ A, const ushort* __restrict__ Bt,
    const float* __restrict__ bias, float* __restrict__ Cf,
    ushort* __restrict__ Cb, int M, int K, int do_relu,
    const float* __restrict__ attS, const float* __restrict__ attD,
    float* __restrict__ aSo, float* __restrict__ aDo)
{
    __shared__ short As[64][40];    // +8 pad
    __shared__ short Bs[256][40];
    const int tid  = threadIdx.x;
    const int row0 = blockIdx.x * 64;
    const int lr = tid >> 2;
    const int lk = (tid & 3) * 8;
    const int w    = tid >> 6;
    const int lane = tid & 63;
    const int cix  = lane & 15;
    const int mrow = 16 * w + cix;
    const int ksel = (lane >> 4) * 8;

    floatx4 acc[16];
#pragma unroll
    for (int c = 0; c < 16; ++c) acc[c] = (floatx4){0.f, 0.f, 0.f, 0.f};

    for (int k0 = 0; k0 < K; k0 += 32) {
        short8 av = {0,0,0,0,0,0,0,0};
        if (row0 + lr < M)
            av = *(const short8*)(A + (size_t)(row0 + lr) * K + k0 + lk);
        *(short8*)&As[lr][lk] = av;
#pragma unroll
        for (int q = 0; q < 4; ++q)
            *(short8*)&Bs[lr + 64 * q][lk] =
                *(const short8*)(Bt + (size_t)(lr + 64 * q) * K + k0 + lk);
        __syncthreads();
        const short8 af = *(const short8*)&As[mrow][ksel];
#pragma unroll
        for (int c = 0; c < 16; ++c) {
            const short8 bf = *(const short8*)&Bs[16 * c + cix][ksel];
            acc[c] = __builtin_amdgcn_mfma_f32_16x16x32_bf16(af, bf, acc[c], 0, 0, 0);
        }
        __syncthreads();
    }

    const int rbase = row0 + 16 * w + (lane >> 4) * 4;
#pragma unroll
    for (int c = 0; c < 16; ++c) {
        const int col = 16 * c + cix;
        const float bv = bias ? bias[col] : 0.f;
#pragma unroll
        for (int i = 0; i < 4; ++i) {
            const int row = rbase + i;
            if (row < M) {
                float v = acc[c][i] + bv;
                if (do_relu) v = fmaxf(v, 0.f);
                const size_t off = (size_t)row * 256 + col;
                if (Cf) Cf[off] = v;
                if (Cb) Cb[off] = f2bf(v);
            }
        }
    }

    // fused per-row attention dots (raw fp32 acc, pre-bias/relu), 4 heads
    if (attS) {
        float sA[4][4], sD[4][4];
#pragma unroll
        for (int h = 0; h < 4; ++h)
#pragma unroll
            for (int i = 0; i < 4; ++i) { sA[h][i] = 0.f; sD[h][i] = 0.f; }
#pragma unroll
        for (int c = 0; c < 16; ++c) {
            const int h = c >> 2;
            const float as_v = attS[16 * c + cix];
            const float ad_v = attD ? attD[16 * c + cix] : 0.f;
#pragma unroll
            for (int i = 0; i < 4; ++i) {
                sA[h][i] += acc[c][i] * as_v;
                sD[h][i] += acc[c][i] * ad_v;
            }
        }
#pragma unroll
        for (int off = 1; off < 16; off <<= 1) {
#pragma unroll
            for (int h = 0; h < 4; ++h)
#pragma unroll
                for (int i = 0; i < 4; ++i) {
                    sA[h][i] += __shfl_xor(sA[h][i], off);
                    sD[h][i] += __shfl_xor(sD[h][i], off);
                }
        }
        if (cix == 0) {
#pragma unroll
            for (int i = 0; i < 4; ++i) {
                const int row = rbase + i;
                if (row < M) {
#pragma unroll
                    for (int h = 0; h < 4; ++h) {
                        aSo[(size_t)row * 4 + h] = sA[h][i];
                        if (aDo) aDo[(size_t)row * 4 + h] = sD[h][i];
                    }
                }
            }
        }
    }
}

// ------ fold ct-dst attention through the projection: wfold[k,h] ------------
__global__ void fold_ct(const float* __restrict__ W, const float* __restrict__ ad,
                        float* __restrict__ wfold)
{
    int idx = blockIdx.x * blockDim.x + threadIdx.x; // 1024 = 256*4
    if (idx >= 1024) return;
    int k = idx >> 2, h = idx & 3;
    float s = 0.f;
#pragma unroll 8
    for (int c = 0; c < 64; ++c) s += W[(size_t)k * 256 + h * 64 + c] * ad[h * 64 + c];
    wfold[idx] = s;
}

// aD[n,h] = ht[n,:] @ wfold[:,h]   (ht in bf16)
__global__ __launch_bounds__(256) void alpha_from_fold(
    const ushort* __restrict__ ht, const float* __restrict__ wfold,
    float* __restrict__ aD, int N)
{
    __shared__ float wf[1024];
    const int tid = threadIdx.x;
    *(float4*)&wf[tid * 4] = *(const float4*)&wfold[tid * 4];
    __syncthreads();
    const int idx = blockIdx.x * 256 + tid;
    if (idx >= N * 4) return;
    const int n = idx >> 2, h = idx & 3;
    const ushort* row = ht + (size_t)n * 256;
    float s = 0.f;
#pragma unroll
    for (int k = 0; k < 256; k += 4) {
        ushort4 r4 = *(const ushort4*)(row + k);
        s += bf2f(r4.x) * wf[(k + 0) * 4 + h] + bf2f(r4.y) * wf[(k + 1) * 4 + h]
           + bf2f(r4.z) * wf[(k + 2) * 4 + h] + bf2f(r4.w) * wf[(k + 3) * 4 + h];
    }
    aD[idx] = s;
}

// ---- topology-only bucket build, XCD-range-partitioned, int payload --------
__global__ __launch_bounds__(256) void build_buckets_tt_ranged(
    const int* __restrict__ src, const int* __restrict__ dst, int E, int RS,
    int* __restrict__ cntA, int* __restrict__ bktA,
    int* __restrict__ cntB, int* __restrict__ bktB)
{
    const int range = blockIdx.x & (NRANGE - 1);
    const int lo = range * RS, hi = lo + RS;
    const int nb = gridDim.x >> 3;            // blocks per range
    const int j  = blockIdx.x >> 3;
    const int stride = nb * blockDim.x;
    for (int e = j * blockDim.x + threadIdx.x; e < E; e += stride) {
        const int s = src[e], d = dst[e];
        if (d >= lo && d < hi) {
            const int pa = atomicAdd(&cntA[d], 1);
            if (pa < CAP) bktA[(size_t)d * CAP + pa] = s;
        }
        if (s >= lo && s < hi) {
            const int pb = atomicAdd(&cntB[s], 1);
            if (pb < CAP) bktB[(size_t)s * CAP + pb] = d;
        }
    }
}

__global__ __launch_bounds__(256) void build_bucket_ranged(
    const int* __restrict__ src, const int* __restrict__ dst, int E, int RS,
    int* __restrict__ cnt, int* __restrict__ bkt)
{
    const int range = blockIdx.x & (NRANGE - 1);
    const int lo = range * RS, hi = lo + RS;
    const int nb = gridDim.x >> 3;
    const int j  = blockIdx.x >> 3;
    const int stride = nb * blockDim.x;
    for (int e = j * blockDim.x + threadIdx.x; e < E; e += stride) {
        const int s = src[e], d = dst[e];
        if (d >= lo && d < hi) {
            const int p = atomicAdd(&cnt[d], 1);
            if (p < CAP) bkt[(size_t)d * CAP + p] = s;
        }
    }
}

// ---- one GAT accumulation phase (inlined 3x in the fused gather) -----------
// Unroll-8 main loop: 8 partner indices, 8 alpha loads, 8 row loads all
// independent -> deep MLP for the latency-bound scattered reads.
__device__ __forceinline__ void gat_phase(
    int n, int h, int c4, int deg,
    const int* __restrict__ bkt,
    const float* __restrict__ aS, float aSn_self, float aDn,
    const ushort* __restrict__ X, const float* __restrict__ bias,
    float scale, int has_self, float4& out)
{
    float4 f = {0.f, 0.f, 0.f, 0.f};
    float den = 0.f;
    if (has_self) {
        float a = aSn_self + aDn;
        a = (a >= 0.f) ? a : LRELU_SLOPE * a;
        const float w = __expf(a);
        const ushort4 x = *(const ushort4*)(X + (size_t)n * 256 + c4);
        f.x = w * bf2f(x.x); f.y = w * bf2f(x.y);
        f.z = w * bf2f(x.z); f.w = w * bf2f(x.w);
        den = w;
    }
    const int* b = bkt + (size_t)n * CAP;
    int i = 0;
    for (; i + 8 <= deg; i += 8) {
        int s[8];
#pragma unroll
        for (int j = 0; j < 8; ++j) s[j] = b[i + j];
        float wv[8];
#pragma unroll
        for (int j = 0; j < 8; ++j) {
            float a = aS[(size_t)s[j] * 4 + h] + aDn;
            a = (a >= 0.f) ? a : LRELU_SLOPE * a;
            wv[j] = __expf(a);
        }
        ushort4 x[8];
#pragma unroll
        for (int j = 0; j < 8; ++j)
            x[j] = *(const ushort4*)(X + (size_t)s[j] * 256 + c4);
#pragma unroll
        for (int j = 0; j < 8; ++j) {
            f.x += wv[j] * bf2f(x[j].x);
            f.y += wv[j] * bf2f(x[j].y);
            f.z += wv[j] * bf2f(x[j].z);
            f.w += wv[j] * bf2f(x[j].w);
            den += wv[j];
        }
    }
    for (; i + 4 <= deg; i += 4) {
        int s[4];
#pragma unroll
        for (int j = 0; j < 4; ++j) s[j] = b[i + j];
        float wv[4];
#pragma unroll
        for (int j = 0; j < 4; ++j) {
            float a = aS[(size_t)s[j] * 4 + h] + aDn;
            a = (a >= 0.f) ? a : LRELU_SLOPE * a;
            wv[j] = __expf(a);
        }
        ushort4 x[4];
#pragma unroll
        for (int j = 0; j < 4; ++j)
            x[j] = *(const ushort4*)(X + (size_t)s[j] * 256 + c4);
#pragma unroll
        for (int j = 0; j < 4; ++j) {
            f.x += wv[j] * bf2f(x[j].x);
            f.y += wv[j] * bf2f(x[j].y);
            f.z += wv[j] * bf2f(x[j].z);
            f.w += wv[j] * bf2f(x[j].w);
            den += wv[j];
        }
    }
    for (; i < deg; ++i) {
        const int s = b[i];
        float a = aS[(size_t)s * 4 + h] + aDn;
        a = (a >= 0.f) ? a : LRELU_SLOPE * a;
        const float w = __expf(a);
        const ushort4 x = *(const ushort4*)(X + (size_t)s * 256 + c4);
        f.x += w * bf2f(x.x); f.y += w * bf2f(x.y);
        f.z += w * bf2f(x.z); f.w += w * bf2f(x.w);
        den += w;
    }
    const float inv = 1.f / fmaxf(den, 1e-16f);
    const float4 bv = *(const float4*)(bias + c4);
    out.x += scale * (f.x * inv + bv.x);
    out.y += scale * (f.y * inv + bv.y);
    out.z += scale * (f.z * inv + bv.z);
    out.w += scale * (f.w * inv + bv.w);
}

// ---- fused gather: all 3 GATs + skip + relu + bf16 cast, one wave/node -----
__global__ __launch_bounds__(256) void gat_gather_fused(
    const int* __restrict__ cntA, const int* __restrict__ bktA,
    const float* __restrict__ aS1, const float* __restrict__ aD1,
    const ushort* __restrict__ P1, const float* __restrict__ b1,
    const int* __restrict__ cntB, const int* __restrict__ bktB,
    const float* __restrict__ aS2, const float* __restrict__ aD2,
    const ushort* __restrict__ P2, const float* __restrict__ b2,
    const int* __restrict__ cntC, const int* __restrict__ bktC,
    const float* __restrict__ aSc, const float* __restrict__ aDc,
    const ushort* __restrict__ Pc, const float* __restrict__ b3,
    ushort* __restrict__ htb, int N)
{
    const int n = blockIdx.x * 4 + (threadIdx.x >> 6);
    if (n >= N) return;
    const int lane = threadIdx.x & 63;
    const int h  = lane >> 4;          // 16 lanes per head
    const int c4 = lane << 2;          // channel base, 0..252

    // hoist all per-node scalars: independent loads issue together
    const int degA = min(cntA[n], CAP);
    const int degB = min(cntB[n], CAP);
    const int degC = min(cntC[n], CAP);
    const float aD1n = aD1[(size_t)n * 4 + h];
    const float aD2n = aD2[(size_t)n * 4 + h];
    const float aDcn = aDc[(size_t)n * 4 + h];
    const float aS1n = aS1[(size_t)n * 4 + h];
    const float aS2n = aS2[(size_t)n * 4 + h];

    float4 out = {0.f, 0.f, 0.f, 0.f};
    gat_phase(n, h, c4, degA, bktA, aS1, aS1n, aD1n, P1, b1, 0.25f, 1, out);
    gat_phase(n, h, c4, degB, bktB, aS2, aS2n, aD2n, P2, b2, 0.25f, 1, out);
    gat_phase(n, h, c4, degC, bktC, aSc, 0.f, aDcn, Pc, b3, 0.50f, 0, out);

    ushort* hp = htb + (size_t)n * 256 + c4;
    const ushort4 hb = *(const ushort4*)hp;
    ushort4 o;
    o.x = f2bf(fmaxf(out.x + bf2f(hb.x), 0.f));
    o.y = f2bf(fmaxf(out.y + bf2f(hb.y), 0.f));
    o.z = f2bf(fmaxf(out.z + bf2f(hb.z), 0.f));
    o.w = f2bf(fmaxf(out.w + bf2f(hb.w), 0.f));
    *(ushort4*)hp = o;
}

// ---------------------------------------------------------------------------
extern "C" void kernel_launch(void* const* d_in, const int* in_sizes, int n_in,
                              void* d_out, int out_size, void* d_ws, size_t ws_size,
                              hipStream_t stream)
{
    const int NT   = in_sizes[0] / 128;
    const int NC   = in_sizes[1] / 64;
    const int E_TT = in_sizes[2] / 2;
    const int E_CT = in_sizes[3];

    const float* x_target = (const float*)d_in[0];
    const float* x_context= (const float*)d_in[1];
    const int*   ei_tt    = (const int*)d_in[2];
    const int*   ei_ct_src= (const int*)d_in[3];
    const int*   ei_ct_dst= (const int*)d_in[4];
    const float* Wt   = (const float*)d_in[5];
    const float* bt   = (const float*)d_in[6];
    const float* Wc   = (const float*)d_in[7];
    const float* bc   = (const float*)d_in[8];
    const float* W_s2d  = (const float*)d_in[9];
    const float* as_s2d = (const float*)d_in[10];
    const float* ad_s2d = (const float*)d_in[11];
    const float* b_s2d  = (const float*)d_in[12];
    const float* W_d2s  = (const float*)d_in[13];
    const float* as_d2s = (const float*)d_in[14];
    const float* ad_d2s = (const float*)d_in[15];
    const float* b_d2s  = (const float*)d_in[16];
    const float* W_ct_src = (const float*)d_in[17];
    const float* W_ct_dst = (const float*)d_in[18];
    const float* as_ct  = (const float*)d_in[19];
    const float* ad_ct  = (const float*)d_in[20];
    const float* b_ct   = (const float*)d_in[21];
    const float* W_out  = (const float*)d_in[22];
    const float* b_out  = (const float*)d_in[23];
    float* out = (float*)d_out;

    const int* tt_src = ei_tt;
    const int* tt_dst = ei_tt + E_TT;

    // ---- workspace carve-up (units: fp32 slots) ----
    float* ws = (float*)d_ws;
    size_t o = 0;
    ushort* htb = (ushort*)(ws + o);   o += (size_t)NT * 128;   // NT*256 bf16
    ushort* Pb1 = (ushort*)(ws + o);   o += (size_t)NT * 128;
    ushort* Pb2 = (ushort*)(ws + o);   o += (size_t)NT * 128;
    ushort* hcb = (ushort*)(ws + o);   o += (size_t)NC * 128;
    ushort* PSb = (ushort*)(ws + o);   o += (size_t)NC * 128;
    ushort* xtb = (ushort*)(ws + o);   o += (size_t)NT * 64;    // NT*128 bf16
    ushort* xcb = (ushort*)(ws + o);   o += (size_t)NC * 32;
    int* bktA = (int*)(ws + o);        o += (size_t)NT * CAP;   // int payload
    int* bktB = (int*)(ws + o);        o += (size_t)NT * CAP;
    int* bktC = (int*)(ws + o);        o += (size_t)NT * CAP;
    float* aS1 = ws + o;               o += (size_t)NT * 4;
    float* aD1 = ws + o;               o += (size_t)NT * 4;
    float* aS2 = ws + o;               o += (size_t)NT * 4;
    float* aD2 = ws + o;               o += (size_t)NT * 4;
    float* aSc = ws + o;               o += (size_t)NT * 4;     // used: NC*4
    float* aDc = ws + o;               o += (size_t)NT * 4;
    int*   cntA = (int*)(ws + o);      o += (size_t)NT;
    int*   cntB = (int*)(ws + o);      o += (size_t)NT;
    int*   cntC = (int*)(ws + o);      o += (size_t)NT;
    float* wfold = ws + o;             o += 1024;
    ushort* WtT   = (ushort*)(ws + o); o += 128 * 256 / 2;
    ushort* WcT   = (ushort*)(ws + o); o += 64 * 256 / 2;
    ushort* Ws2dT = (ushort*)(ws + o); o += 256 * 256 / 2;
    ushort* Wd2sT = (ushort*)(ws + o); o += 256 * 256 / 2;
    ushort* WctsT = (ushort*)(ws + o); o += 256 * 256 / 2;
    ushort* WoutT = (ushort*)(ws + o); o += 256 * 256 / 2;
    (void)ws_size; (void)n_in; (void)out_size;

    const dim3 blk(256);
    const int gN4 = (NT * 4 + 255) / 256;
    const int gGat = (NT + 3) / 4;
    const int RS = (NT + NRANGE - 1) / NRANGE;   // node-range size per XCD

    auto gemm = [&](const ushort* A, const ushort* Bt, const float* bias,
                    float* Cf, ushort* Cb, int M, int K, int relu,
                    const float* attS, const float* attD, float* aSo, float* aDo) {
        dim3 grid((M + 63) / 64);
        hipLaunchKernelGGL(gemm_bf16, grid, blk, 0, stream, A, Bt, bias, Cf, Cb,
                           M, K, relu, attS, attD, aSo, aDo);
    };

    // 0) casts, weight transposes, topology buckets (feature-independent)
    hipMemsetAsync(cntA, 0, (size_t)NT * 3 * sizeof(int), stream); // A,B,C contiguous
    hipLaunchKernelGGL(cast_bf16, dim3((NT * 128 / 4 + 255) / 256), blk, 0, stream,
                       x_target, xtb, NT * 128 / 4);
    hipLaunchKernelGGL(cast_bf16, dim3((NC * 64 / 4 + 255) / 256), blk, 0, stream,
                       x_context, xcb, NC * 64 / 4);
    hipLaunchKernelGGL(wtrans, dim3(128), blk, 0, stream, Wt, WtT, 128);
    hipLaunchKernelGGL(wtrans, dim3(64),  blk, 0, stream, Wc, WcT, 64);
    hipLaunchKernelGGL(wtrans, dim3(256), blk, 0, stream, W_s2d, Ws2dT, 256);
    hipLaunchKernelGGL(wtrans, dim3(256), blk, 0, stream, W_d2s, Wd2sT, 256);
    hipLaunchKernelGGL(wtrans, dim3(256), blk, 0, stream, W_ct_src, WctsT, 256);
    hipLaunchKernelGGL(wtrans, dim3(256), blk, 0, stream, W_out, WoutT, 256);
    hipLaunchKernelGGL(build_buckets_tt_ranged, dim3(64 * NRANGE), blk, 0, stream,
                       tt_src, tt_dst, E_TT, RS, cntA, bktA, cntB, bktB);
    hipLaunchKernelGGL(build_bucket_ranged, dim3(64 * NRANGE), blk, 0, stream,
                       ei_ct_src, ei_ct_dst, E_CT, RS, cntC, bktC);

    // 1) pretransform
    gemm(xtb, WtT, bt, nullptr, htb, NT, 128, 1, nullptr, nullptr, nullptr, nullptr);
    gemm(xcb, WcT, bc, nullptr, hcb, NC, 64, 1, nullptr, nullptr, nullptr, nullptr);

    // 2) all three GAT projections + attention alphas
    gemm(htb, Ws2dT, nullptr, nullptr, Pb1, NT, 256, 0, as_s2d, ad_s2d, aS1, aD1);
    gemm(htb, Wd2sT, nullptr, nullptr, Pb2, NT, 256, 0, as_d2s, ad_d2s, aS2, aD2);
    gemm(hcb, WctsT, nullptr, nullptr, PSb, NC, 256, 0, as_ct, nullptr, aSc, nullptr);
    hipLaunchKernelGGL(fold_ct, dim3(4), blk, 0, stream, W_ct_dst, ad_ct, wfold);
    hipLaunchKernelGGL(alpha_from_fold, dim3(gN4), blk, 0, stream, htb, wfold, aDc, NT);

    // 3) single fused gather: s2d + d2s + ct + skip + relu + bf16 cast
    hipLaunchKernelGGL(gat_gather_fused, dim3(gGat), blk, 0, stream,
                       cntA, bktA, aS1, aD1, Pb1, b_s2d,
                       cntB, bktB, aS2, aD2, Pb2, b_d2s,
                       cntC, bktC, aSc, aDc, PSb, b_ct,
                       htb, NT);

    // 4) final linear
    gemm(htb, WoutT, b_out, out, nullptr, NT, 256, 0, nullptr, nullptr, nullptr, nullptr);
}

// Round 6
// 405.253 us; speedup vs baseline: 1.3931x; 1.3931x over previous
//
#include <hip/hip_runtime.h>
#include <hip/hip_bf16.h>
#include <cstdint>
#include <cstddef>

// ---------------------------------------------------------------------------
// STGNN forward. Round 11 == Round 9 (third submission; prior two failures
// were broker-level container failures, not kernel verdicts).
//  - R9: R7 hot loops verbatim + launch-count reduction (20 -> 10):
//      prep_all        = 2 casts + 6 wtrans     (8 launches -> 1)
//      build_all       = tt + ct bucket builds  (2 -> 1)
//      gemm_proj3      = 3 projection GEMMs     (3 -> 1, blockIdx.y ranges)
//  - R8 post-mortem stands: gather unroll-8 and 64x256 GEMM both regressed
//    (occupancy loss / parallelism loss); R7 forms restored.
// ---------------------------------------------------------------------------

#define LRELU_SLOPE 0.2f
#define CAP 64
#define NRANGE 8

typedef __attribute__((ext_vector_type(8))) short short8;
typedef __attribute__((ext_vector_type(4))) float floatx4;

__device__ __forceinline__ float bf2f(ushort u) {
    union { unsigned int u32; float f; } v; v.u32 = ((unsigned int)u) << 16; return v.f;
}
__device__ __forceinline__ ushort f2bf(float x) {
    union { float f; unsigned int u; } v; v.f = x;
    unsigned int r = (v.u + 0x7FFFu + ((v.u >> 16) & 1u)) >> 16;
    return (ushort)r;
}

// ---- prep_all: x_target cast | x_context cast | 6x weight transpose -------
// One segmented grid; segment bounds passed as args.
__global__ __launch_bounds__(256) void prep_all(
    const float* __restrict__ xt, ushort* __restrict__ xtb,
    const float* __restrict__ xc, ushort* __restrict__ xcb,
    const float* __restrict__ Wt,  ushort* __restrict__ WtT,
    const float* __restrict__ Wc,  ushort* __restrict__ WcT,
    const float* __restrict__ W1,  ushort* __restrict__ W1T,
    const float* __restrict__ W2,  ushort* __restrict__ W2T,
    const float* __restrict__ W3,  ushort* __restrict__ W3T,
    const float* __restrict__ W4,  ushort* __restrict__ W4T,
    int s0, int s1, int s2, int s3, int s4, int s5, int s6, int s7)
{
    const int idx = blockIdx.x * blockDim.x + threadIdx.x;
    if (idx < s0) {                       // x_target: float4 -> ushort4
        float4 v = ((const float4*)xt)[idx];
        ushort4 o;
        o.x = f2bf(v.x); o.y = f2bf(v.y); o.z = f2bf(v.z); o.w = f2bf(v.w);
        ((ushort4*)xtb)[idx] = o;
    } else if (idx < s1) {                // x_context
        const int i = idx - s0;
        float4 v = ((const float4*)xc)[i];
        ushort4 o;
        o.x = f2bf(v.x); o.y = f2bf(v.y); o.z = f2bf(v.z); o.w = f2bf(v.w);
        ((ushort4*)xcb)[i] = o;
    } else if (idx < s2) {                // Wt [128][256]
        const int i = idx - s1, k = i >> 8, n = i & 255;
        WtT[n * 128 + k] = f2bf(Wt[i]);
    } else if (idx < s3) {                // Wc [64][256]
        const int i = idx - s2, k = i >> 8, n = i & 255;
        WcT[n * 64 + k] = f2bf(Wc[i]);
    } else if (idx < s4) {                // W_s2d [256][256]
        const int i = idx - s3, k = i >> 8, n = i & 255;
        W1T[n * 256 + k] = f2bf(W1[i]);
    } else if (idx < s5) {                // W_d2s
        const int i = idx - s4, k = i >> 8, n = i & 255;
        W2T[n * 256 + k] = f2bf(W2[i]);
    } else if (idx < s6) {                // W_ct_src
        const int i = idx - s5, k = i >> 8, n = i & 255;
        W3T[n * 256 + k] = f2bf(W3[i]);
    } else if (idx < s7) {                // W_out
        const int i = idx - s6, k = i >> 8, n = i & 255;
        W4T[n * 256 + k] = f2bf(W4[i]);
    }
}

// ---------------- bf16 MFMA GEMM core (R7 64x64-tile form) ------------------
__device__ __forceinline__ void gemm_core(
    const ushort* __restrict__ A, const ushort* __restrict__ Bt,
    const float* __restrict__ bias, float* __restrict__ Cf,
    ushort* __restrict__ Cb, int M, int K, int do_relu,
    const float* __restrict__ attS, const float* __restrict__ attD,
    float* __restrict__ aSo, float* __restrict__ aDo,
    int row0, int col0)
{
    __shared__ short As[64][40];   // +8 pad
    __shared__ short Bs[64][40];
    const int tid  = threadIdx.x;
    const int lr = tid >> 2;
    const int lk = (tid & 3) * 8;
    const int w    = tid >> 6;
    const int lane = tid & 63;
    const int mrow = 16 * w + (lane & 15);
    const int ksel = (lane >> 4) * 8;

    floatx4 acc0 = {0.f,0.f,0.f,0.f}, acc1 = acc0, acc2 = acc0, acc3 = acc0;

    for (int k0 = 0; k0 < K; k0 += 32) {
        short8 av = {0,0,0,0,0,0,0,0};
        if (row0 + lr < M)
            av = *(const short8*)(A + (size_t)(row0 + lr) * K + k0 + lk);
        *(short8*)&As[lr][lk] = av;
        *(short8*)&Bs[lr][lk] =
            *(const short8*)(Bt + (size_t)(col0 + lr) * K + k0 + lk);
        __syncthreads();
        short8 af = *(const short8*)&As[mrow][ksel];
        short8 b0 = *(const short8*)&Bs[ 0 + (lane & 15)][ksel];
        short8 b1 = *(const short8*)&Bs[16 + (lane & 15)][ksel];
        short8 b2 = *(const short8*)&Bs[32 + (lane & 15)][ksel];
        short8 b3 = *(const short8*)&Bs[48 + (lane & 15)][ksel];
        acc0 = __builtin_amdgcn_mfma_f32_16x16x32_bf16(af, b0, acc0, 0, 0, 0);
        acc1 = __builtin_amdgcn_mfma_f32_16x16x32_bf16(af, b1, acc1, 0, 0, 0);
        acc2 = __builtin_amdgcn_mfma_f32_16x16x32_bf16(af, b2, acc2, 0, 0, 0);
        acc3 = __builtin_amdgcn_mfma_f32_16x16x32_bf16(af, b3, acc3, 0, 0, 0);
        __syncthreads();
    }

    const int rbase = row0 + 16 * w + (lane >> 4) * 4;
    floatx4 av[4] = {acc0, acc1, acc2, acc3};
#pragma unroll
    for (int c = 0; c < 4; ++c) {
        const int col = col0 + 16 * c + (lane & 15);
        const float bv = bias ? bias[col] : 0.f;
#pragma unroll
        for (int i = 0; i < 4; ++i) {
            const int row = rbase + i;
            if (row < M) {
                float v = av[c][i] + bv;
                if (do_relu) v = fmaxf(v, 0.f);
                const size_t off = (size_t)row * 256 + col;
                if (Cf) Cf[off] = v;
                if (Cb) Cb[off] = f2bf(v);
            }
        }
    }

    // fused per-row attention dots (raw fp32 acc, pre-bias/relu)
    if (attS) {
        const int cix = lane & 15;
        float sA[4] = {0.f,0.f,0.f,0.f}, sD[4] = {0.f,0.f,0.f,0.f};
#pragma unroll
        for (int c = 0; c < 4; ++c) {
            const float as_v = attS[col0 + 16 * c + cix];
            const float ad_v = attD ? attD[col0 + 16 * c + cix] : 0.f;
#pragma unroll
            for (int i = 0; i < 4; ++i) {
                sA[i] += av[c][i] * as_v;
                sD[i] += av[c][i] * ad_v;
            }
        }
#pragma unroll
        for (int off = 1; off < 16; off <<= 1) {
#pragma unroll
            for (int i = 0; i < 4; ++i) {
                sA[i] += __shfl_xor(sA[i], off);
                sD[i] += __shfl_xor(sD[i], off);
            }
        }
        if (cix == 0) {
            const int head = col0 >> 6;
#pragma unroll
            for (int i = 0; i < 4; ++i) {
                const int row = rbase + i;
                if (row < M) {
                    aSo[(size_t)row * 4 + head] = sA[i];
                    if (aDo) aDo[(size_t)row * 4 + head] = sD[i];
                }
            }
        }
    }
}

// ---- standalone GEMM (pretransforms + final): grid (M/64, 4) ---------------
__global__ __launch_bounds__(256) void gemm_bf16(
    const ushort* __restrict__ A, const ushort* __restrict__ Bt,
    const float* __restrict__ bias, float* __restrict__ Cf,
    ushort* __restrict__ Cb, int M, int K, int do_relu)
{
    const int row0 = blockIdx.x * 64;
    if (row0 >= M) return;
    gemm_core(A, Bt, bias, Cf, Cb, M, K, do_relu,
              nullptr, nullptr, nullptr, nullptr, row0, blockIdx.y * 64);
}

// ---- merged projection GEMM: y in [0,12) selects {s2d, d2s, ct-src} -------
__global__ __launch_bounds__(256) void gemm_proj3(
    const ushort* __restrict__ htb, const ushort* __restrict__ hcb,
    const ushort* __restrict__ W1T, const ushort* __restrict__ W2T,
    const ushort* __restrict__ W3T,
    ushort* __restrict__ Pb1, ushort* __restrict__ Pb2, ushort* __restrict__ PSb,
    const float* __restrict__ as1, const float* __restrict__ ad1,
    const float* __restrict__ as2, const float* __restrict__ ad2,
    const float* __restrict__ asc,
    float* __restrict__ aS1, float* __restrict__ aD1,
    float* __restrict__ aS2, float* __restrict__ aD2,
    float* __restrict__ aSc, int NT, int NC)
{
    const int y = blockIdx.y;
    const int row0 = blockIdx.x * 64;
    if (y < 4) {
        if (row0 >= NT) return;
        gemm_core(htb, W1T, nullptr, nullptr, Pb1, NT, 256, 0,
                  as1, ad1, aS1, aD1, row0, y * 64);
    } else if (y < 8) {
        if (row0 >= NT) return;
        gemm_core(htb, W2T, nullptr, nullptr, Pb2, NT, 256, 0,
                  as2, ad2, aS2, aD2, row0, (y - 4) * 64);
    } else {
        if (row0 >= NC) return;
        gemm_core(hcb, W3T, nullptr, nullptr, PSb, NC, 256, 0,
                  asc, nullptr, aSc, nullptr, row0, (y - 8) * 64);
    }
}

// ------ fold ct-dst attention through the projection: wfold[k,h] ------------
__global__ void fold_ct(const float* __restrict__ W, const float* __restrict__ ad,
                        float* __restrict__ wfold)
{
    int idx = blockIdx.x * blockDim.x + threadIdx.x; // 1024 = 256*4
    if (idx >= 1024) return;
    int k = idx >> 2, h = idx & 3;
    float s = 0.f;
#pragma unroll 8
    for (int c = 0; c < 64; ++c) s += W[(size_t)k * 256 + h * 64 + c] * ad[h * 64 + c];
    wfold[idx] = s;
}

// aD[n,h] = ht[n,:] @ wfold[:,h]   (ht in bf16)
__global__ __launch_bounds__(256) void alpha_from_fold(
    const ushort* __restrict__ ht, const float* __restrict__ wfold,
    float* __restrict__ aD, int N)
{
    __shared__ float wf[1024];
    const int tid = threadIdx.x;
    *(float4*)&wf[tid * 4] = *(const float4*)&wfold[tid * 4];
    __syncthreads();
    const int idx = blockIdx.x * 256 + tid;
    if (idx >= N * 4) return;
    const int n = idx >> 2, h = idx & 3;
    const ushort* row = ht + (size_t)n * 256;
    float s = 0.f;
#pragma unroll
    for (int k = 0; k < 256; k += 4) {
        ushort4 r4 = *(const ushort4*)(row + k);
        s += bf2f(r4.x) * wf[(k + 0) * 4 + h] + bf2f(r4.y) * wf[(k + 1) * 4 + h]
           + bf2f(r4.z) * wf[(k + 2) * 4 + h] + bf2f(r4.w) * wf[(k + 3) * 4 + h];
    }
    aD[idx] = s;
}

// ---- merged topology bucket build: blocks [0,512) tt, [512,1024) ct --------
// XCD-range-partitioned (range = bx&7), int payload (partner node only).
__global__ __launch_bounds__(256) void build_all_buckets(
    const int* __restrict__ tt_src, const int* __restrict__ tt_dst, int E_tt,
    const int* __restrict__ ct_src, const int* __restrict__ ct_dst, int E_ct,
    int RS,
    int* __restrict__ cntA, int* __restrict__ bktA,
    int* __restrict__ cntB, int* __restrict__ bktB,
    int* __restrict__ cntC, int* __restrict__ bktC)
{
    const int bx = (blockIdx.x < 512) ? blockIdx.x : blockIdx.x - 512;
    const int range = bx & (NRANGE - 1);
    const int lo = range * RS, hi = lo + RS;
    const int j  = bx >> 3;                  // 64 blocks per range
    const int stride = 64 * blockDim.x;
    if (blockIdx.x < 512) {
        for (int e = j * blockDim.x + threadIdx.x; e < E_tt; e += stride) {
            const int s = tt_src[e], d = tt_dst[e];
            if (d >= lo && d < hi) {
                const int pa = atomicAdd(&cntA[d], 1);
                if (pa < CAP) bktA[(size_t)d * CAP + pa] = s;
            }
            if (s >= lo && s < hi) {
                const int pb = atomicAdd(&cntB[s], 1);
                if (pb < CAP) bktB[(size_t)s * CAP + pb] = d;
            }
        }
    } else {
        for (int e = j * blockDim.x + threadIdx.x; e < E_ct; e += stride) {
            const int s = ct_src[e], d = ct_dst[e];
            if (d >= lo && d < hi) {
                const int p = atomicAdd(&cntC[d], 1);
                if (p < CAP) bktC[(size_t)d * CAP + p] = s;
            }
        }
    }
}

// ---- one GAT accumulation phase (R7 verbatim; inlined 3x in fused gather) --
__device__ __forceinline__ void gat_phase(
    int n, int h, int c4,
    const int* __restrict__ cnt, const int* __restrict__ bkt,
    const float* __restrict__ aS, const float* __restrict__ aD,
    const ushort* __restrict__ X, const float* __restrict__ bias,
    float scale, int has_self, float4& out)
{
    const float aDn = aD[(size_t)n * 4 + h];
    float4 f = {0.f, 0.f, 0.f, 0.f};
    float den = 0.f;
    if (has_self) {
        float a = aS[(size_t)n * 4 + h] + aDn;
        a = (a >= 0.f) ? a : LRELU_SLOPE * a;
        const float w = __expf(a);
        const ushort4 x = *(const ushort4*)(X + (size_t)n * 256 + c4);
        f.x = w * bf2f(x.x); f.y = w * bf2f(x.y);
        f.z = w * bf2f(x.z); f.w = w * bf2f(x.w);
        den = w;
    }
    const int deg = min(cnt[n], CAP);
    const int* b = bkt + (size_t)n * CAP;
    int i = 0;
    for (; i + 4 <= deg; i += 4) {
        const int s0 = b[i], s1 = b[i + 1], s2 = b[i + 2], s3 = b[i + 3];
        float a0 = aS[(size_t)s0 * 4 + h] + aDn;
        float a1 = aS[(size_t)s1 * 4 + h] + aDn;
        float a2 = aS[(size_t)s2 * 4 + h] + aDn;
        float a3 = aS[(size_t)s3 * 4 + h] + aDn;
        a0 = (a0 >= 0.f) ? a0 : LRELU_SLOPE * a0;
        a1 = (a1 >= 0.f) ? a1 : LRELU_SLOPE * a1;
        a2 = (a2 >= 0.f) ? a2 : LRELU_SLOPE * a2;
        a3 = (a3 >= 0.f) ? a3 : LRELU_SLOPE * a3;
        const float w0 = __expf(a0), w1 = __expf(a1);
        const float w2 = __expf(a2), w3 = __expf(a3);
        const ushort4 x0 = *(const ushort4*)(X + (size_t)s0 * 256 + c4);
        const ushort4 x1 = *(const ushort4*)(X + (size_t)s1 * 256 + c4);
        const ushort4 x2 = *(const ushort4*)(X + (size_t)s2 * 256 + c4);
        const ushort4 x3 = *(const ushort4*)(X + (size_t)s3 * 256 + c4);
        f.x += w0 * bf2f(x0.x) + w1 * bf2f(x1.x) + w2 * bf2f(x2.x) + w3 * bf2f(x3.x);
        f.y += w0 * bf2f(x0.y) + w1 * bf2f(x1.y) + w2 * bf2f(x2.y) + w3 * bf2f(x3.y);
        f.z += w0 * bf2f(x0.z) + w1 * bf2f(x1.z) + w2 * bf2f(x2.z) + w3 * bf2f(x3.z);
        f.w += w0 * bf2f(x0.w) + w1 * bf2f(x1.w) + w2 * bf2f(x2.w) + w3 * bf2f(x3.w);
        den += w0 + w1 + w2 + w3;
    }
    for (; i < deg; ++i) {
        const int s = b[i];
        float a = aS[(size_t)s * 4 + h] + aDn;
        a = (a >= 0.f) ? a : LRELU_SLOPE * a;
        const float w = __expf(a);
        const ushort4 x = *(const ushort4*)(X + (size_t)s * 256 + c4);
        f.x += w * bf2f(x.x); f.y += w * bf2f(x.y);
        f.z += w * bf2f(x.z); f.w += w * bf2f(x.w);
        den += w;
    }
    const float inv = 1.f / fmaxf(den, 1e-16f);
    const float4 bv = *(const float4*)(bias + c4);
    out.x += scale * (f.x * inv + bv.x);
    out.y += scale * (f.y * inv + bv.y);
    out.z += scale * (f.z * inv + bv.z);
    out.w += scale * (f.w * inv + bv.w);
}

// ---- fused gather: all 3 GATs + skip + relu + bf16 cast, one wave/node -----
__global__ __launch_bounds__(256) void gat_gather_fused(
    const int* __restrict__ cntA, const int* __restrict__ bktA,
    const float* __restrict__ aS1, const float* __restrict__ aD1,
    const ushort* __restrict__ P1, const float* __restrict__ b1,
    const int* __restrict__ cntB, const int* __restrict__ bktB,
    const float* __restrict__ aS2, const float* __restrict__ aD2,
    const ushort* __restrict__ P2, const float* __restrict__ b2,
    const int* __restrict__ cntC, const int* __restrict__ bktC,
    const float* __restrict__ aSc, const float* __restrict__ aDc,
    const ushort* __restrict__ Pc, const float* __restrict__ b3,
    ushort* __restrict__ htb, int N)
{
    const int n = blockIdx.x * 4 + (threadIdx.x >> 6);
    if (n >= N) return;
    const int lane = threadIdx.x & 63;
    const int h  = lane >> 4;          // 16 lanes per head
    const int c4 = lane << 2;          // channel base, 0..252

    float4 out = {0.f, 0.f, 0.f, 0.f};
    gat_phase(n, h, c4, cntA, bktA, aS1, aD1, P1, b1, 0.25f, 1, out);
    gat_phase(n, h, c4, cntB, bktB, aS2, aD2, P2, b2, 0.25f, 1, out);
    gat_phase(n, h, c4, cntC, bktC, aSc, aDc, Pc, b3, 0.50f, 0, out);

    ushort* hp = htb + (size_t)n * 256 + c4;
    const ushort4 hb = *(const ushort4*)hp;
    ushort4 o;
    o.x = f2bf(fmaxf(out.x + bf2f(hb.x), 0.f));
    o.y = f2bf(fmaxf(out.y + bf2f(hb.y), 0.f));
    o.z = f2bf(fmaxf(out.z + bf2f(hb.z), 0.f));
    o.w = f2bf(fmaxf(out.w + bf2f(hb.w), 0.f));
    *(ushort4*)hp = o;
}

// ---------------------------------------------------------------------------
extern "C" void kernel_launch(void* const* d_in, const int* in_sizes, int n_in,
                              void* d_out, int out_size, void* d_ws, size_t ws_size,
                              hipStream_t stream)
{
    const int NT   = in_sizes[0] / 128;
    const int NC   = in_sizes[1] / 64;
    const int E_TT = in_sizes[2] / 2;
    const int E_CT = in_sizes[3];

    const float* x_target = (const float*)d_in[0];
    const float* x_context= (const float*)d_in[1];
    const int*   ei_tt    = (const int*)d_in[2];
    const int*   ei_ct_src= (const int*)d_in[3];
    const int*   ei_ct_dst= (const int*)d_in[4];
    const float* Wt   = (const float*)d_in[5];
    const float* bt   = (const float*)d_in[6];
    const float* Wc   = (const float*)d_in[7];
    const float* bc   = (const float*)d_in[8];
    const float* W_s2d  = (const float*)d_in[9];
    const float* as_s2d = (const float*)d_in[10];
    const float* ad_s2d = (const float*)d_in[11];
    const float* b_s2d  = (const float*)d_in[12];
    const float* W_d2s  = (const float*)d_in[13];
    const float* as_d2s = (const float*)d_in[14];
    const float* ad_d2s = (const float*)d_in[15];
    const float* b_d2s  = (const float*)d_in[16];
    const float* W_ct_src = (const float*)d_in[17];
    const float* W_ct_dst = (const float*)d_in[18];
    const float* as_ct  = (const float*)d_in[19];
    const float* ad_ct  = (const float*)d_in[20];
    const float* b_ct   = (const float*)d_in[21];
    const float* W_out  = (const float*)d_in[22];
    const float* b_out  = (const float*)d_in[23];
    float* out = (float*)d_out;

    const int* tt_src = ei_tt;
    const int* tt_dst = ei_tt + E_TT;

    // ---- workspace carve-up (units: fp32 slots) ----
    float* ws = (float*)d_ws;
    size_t o = 0;
    ushort* htb = (ushort*)(ws + o);   o += (size_t)NT * 128;   // NT*256 bf16
    ushort* Pb1 = (ushort*)(ws + o);   o += (size_t)NT * 128;
    ushort* Pb2 = (ushort*)(ws + o);   o += (size_t)NT * 128;
    ushort* hcb = (ushort*)(ws + o);   o += (size_t)NC * 128;
    ushort* PSb = (ushort*)(ws + o);   o += (size_t)NC * 128;
    ushort* xtb = (ushort*)(ws + o);   o += (size_t)NT * 64;    // NT*128 bf16
    ushort* xcb = (ushort*)(ws + o);   o += (size_t)NC * 32;
    int* bktA = (int*)(ws + o);        o += (size_t)NT * CAP;   // int payload
    int* bktB = (int*)(ws + o);        o += (size_t)NT * CAP;
    int* bktC = (int*)(ws + o);        o += (size_t)NT * CAP;
    float* aS1 = ws + o;               o += (size_t)NT * 4;
    float* aD1 = ws + o;               o += (size_t)NT * 4;
    float* aS2 = ws + o;               o += (size_t)NT * 4;
    float* aD2 = ws + o;               o += (size_t)NT * 4;
    float* aSc = ws + o;               o += (size_t)NT * 4;     // used: NC*4
    float* aDc = ws + o;               o += (size_t)NT * 4;
    int*   cntA = (int*)(ws + o);      o += (size_t)NT;
    int*   cntB = (int*)(ws + o);      o += (size_t)NT;
    int*   cntC = (int*)(ws + o);      o += (size_t)NT;
    float* wfold = ws + o;             o += 1024;
    ushort* WtT   = (ushort*)(ws + o); o += 128 * 256 / 2;
    ushort* WcT   = (ushort*)(ws + o); o += 64 * 256 / 2;
    ushort* Ws2dT = (ushort*)(ws + o); o += 256 * 256 / 2;
    ushort* Wd2sT = (ushort*)(ws + o); o += 256 * 256 / 2;
    ushort* WctsT = (ushort*)(ws + o); o += 256 * 256 / 2;
    ushort* WoutT = (ushort*)(ws + o); o += 256 * 256 / 2;
    (void)ws_size; (void)n_in; (void)out_size;

    const dim3 blk(256);
    const int gN4 = (NT * 4 + 255) / 256;
    const int gGat = (NT + 3) / 4;
    const int RS = (NT + NRANGE - 1) / NRANGE;   // node-range size per XCD

    // 0) zero bucket counters (A,B,C contiguous)
    hipMemsetAsync(cntA, 0, (size_t)NT * 3 * sizeof(int), stream);

    // 1) prep: casts + all 6 weight transposes, one launch
    const int s0 = NT * 32;            // x_target float4 count
    const int s1 = s0 + NC * 16;       // x_context
    const int s2 = s1 + 128 * 256;     // Wt
    const int s3 = s2 + 64 * 256;      // Wc
    const int s4 = s3 + 65536;         // W_s2d
    const int s5 = s4 + 65536;         // W_d2s
    const int s6 = s5 + 65536;         // W_ct_src
    const int s7 = s6 + 65536;         // W_out
    hipLaunchKernelGGL(prep_all, dim3((s7 + 255) / 256), blk, 0, stream,
                       x_target, xtb, x_context, xcb,
                       Wt, WtT, Wc, WcT, W_s2d, Ws2dT, W_d2s, Wd2sT,
                       W_ct_src, WctsT, W_out, WoutT,
                       s0, s1, s2, s3, s4, s5, s6, s7);

    // 2) topology buckets (tt + ct in one launch)
    hipLaunchKernelGGL(build_all_buckets, dim3(1024), blk, 0, stream,
                       tt_src, tt_dst, E_TT, ei_ct_src, ei_ct_dst, E_CT, RS,
                       cntA, bktA, cntB, bktB, cntC, bktC);

    // 3) ct-dst attention fold (inputs only; early to stay off critical path)
    hipLaunchKernelGGL(fold_ct, dim3(4), blk, 0, stream, W_ct_dst, ad_ct, wfold);

    // 4) pretransforms
    hipLaunchKernelGGL(gemm_bf16, dim3((NT + 63) / 64, 4), blk, 0, stream,
                       xtb, WtT, bt, nullptr, htb, NT, 128, 1);
    hipLaunchKernelGGL(gemm_bf16, dim3((NC + 63) / 64, 4), blk, 0, stream,
                       xcb, WcT, bc, nullptr, hcb, NC, 64, 1);

    // 5) all three GAT projections + attn dots, one launch
    hipLaunchKernelGGL(gemm_proj3, dim3((NT + 63) / 64, 12), blk, 0, stream,
                       htb, hcb, Ws2dT, Wd2sT, WctsT, Pb1, Pb2, PSb,
                       as_s2d, ad_s2d, as_d2s, ad_d2s, as_ct,
                       aS1, aD1, aS2, aD2, aSc, NT, NC);

    // 6) ct-dst alphas from folded projection
    hipLaunchKernelGGL(alpha_from_fold, dim3(gN4), blk, 0, stream,
                       htb, wfold, aDc, NT);

    // 7) single fused gather: s2d + d2s + ct + skip + relu + bf16 cast
    hipLaunchKernelGGL(gat_gather_fused, dim3(gGat), blk, 0, stream,
                       cntA, bktA, aS1, aD1, Pb1, b_s2d,
                       cntB, bktB, aS2, aD2, Pb2, b_d2s,
                       cntC, bktC, aSc, aDc, PSb, b_ct,
                       htb, NT);

    // 8) final linear
    hipLaunchKernelGGL(gemm_bf16, dim3((NT + 63) / 64, 4), blk, 0, stream,
                       htb, WoutT, b_out, out, nullptr, NT, 256, 0);
}